// Round 1
// baseline (493.397 us; speedup 1.0000x reference)
//
#include <hip/hip_runtime.h>
#include <math.h>

#define N 8192
#define D 256
#define MARGIN 1.0f

#define BM 128
#define BN 128
#define BK 32

// ---------------------------------------------------------------------------
// Kernel 1: one wave per anchor.
//   - sq[i]   = ||x_i||^2
//   - dpos[i] = max dist over same-label j != i   (-1 sentinel if none;
//               sentinel behaves identically to reference's -inf in the
//               semi-mask since dist >= 0: dist < (-1+1)=0 is never true)
//   - init minneg/minsemi to +inf bits
// Same-label pairs are ~16/anchor (512 classes), so this is ~0.2% of the
// full pairwise work.
// ---------------------------------------------------------------------------
__global__ __launch_bounds__(256) void k_dpos(const float* __restrict__ x,
                                              const int* __restrict__ labels,
                                              float* __restrict__ sq,
                                              float* __restrict__ dpos,
                                              int* __restrict__ minneg,
                                              int* __restrict__ minsemi) {
    int wave = (blockIdx.x * blockDim.x + threadIdx.x) >> 6;
    int lane = threadIdx.x & 63;
    if (wave >= N) return;
    const int i = wave;

    float4 xi = reinterpret_cast<const float4*>(x + (size_t)i * D)[lane];
    float sqi = xi.x * xi.x + xi.y * xi.y + xi.z * xi.z + xi.w * xi.w;
    for (int m = 32; m >= 1; m >>= 1) sqi += __shfl_xor(sqi, m, 64);

    const int L = labels[i];
    float dp = -1.0f;

    for (int base = 0; base < N; base += 64) {
        int j = base + lane;
        int lj = labels[j];
        unsigned long long ball = __ballot(lj == L && j != i);
        while (ball) {
            int b = __ffsll((unsigned long long)ball) - 1;
            ball &= ball - 1ull;
            int j2 = base + b;
            float4 xj = reinterpret_cast<const float4*>(x + (size_t)j2 * D)[lane];
            float dotp = xi.x * xj.x + xi.y * xj.y + xi.z * xj.z + xi.w * xj.w;
            float sqjp = xj.x * xj.x + xj.y * xj.y + xj.z * xj.z + xj.w * xj.w;
            for (int m = 32; m >= 1; m >>= 1) {
                dotp += __shfl_xor(dotp, m, 64);
                sqjp += __shfl_xor(sqjp, m, 64);
            }
            float sqd = fmaxf(sqi + sqjp - 2.0f * dotp, 0.0f);
            float dist = sqd > 0.0f ? sqrtf(sqd) : 0.0f;
            dp = fmaxf(dp, dist);
        }
    }

    if (lane == 0) {
        sq[i] = sqi;
        dpos[i] = dp;
        minneg[i] = 0x7F800000;   // +inf bits
        minsemi[i] = 0x7F800000;
    }
}

// ---------------------------------------------------------------------------
// Kernel 2: the hot pass. Tiled f32 X*X^T with fused distance/mask epilogue.
// Each block owns a BMxBN tile; per-row partial min_neg/min_semi are reduced
// within the 16-thread row group via shuffles, then one int atomicMin per row
// (dist >= 0, so int-bit compare == float compare; deterministic).
// ---------------------------------------------------------------------------
__global__ __launch_bounds__(256) void k_main(const float* __restrict__ x,
                                              const int* __restrict__ labels,
                                              const float* __restrict__ sq,
                                              const float* __restrict__ dpos,
                                              int* __restrict__ minneg,
                                              int* __restrict__ minsemi) {
    __shared__ float As[BK][BM + 4];
    __shared__ float Bs[BK][BN + 4];
    __shared__ int   rlab[BM];
    __shared__ int   clab[BN];
    __shared__ float rsq[BM], csq[BN], rdp[BM];

    const int nbx = N / BN;
    int bx = blockIdx.x % nbx;
    int by = blockIdx.x / nbx;
    const int r0 = by * BM, c0 = bx * BN;
    const int t = threadIdx.x;
    const int tx = t & 15, ty = t >> 4;

    if (t < BM) {
        rlab[t] = labels[r0 + t];
        rsq[t] = sq[r0 + t];
        rdp[t] = dpos[r0 + t];
    } else {
        int u = t - BM;
        clab[u] = labels[c0 + u];
        csq[u] = sq[c0 + u];
    }

    float acc[8][8] = {};

    for (int k0 = 0; k0 < D; k0 += BK) {
        __syncthreads();
#pragma unroll
        for (int p = 0; p < 4; ++p) {
            int row = (t >> 3) + p * 32;      // 0..127
            int kc = (t & 7) * 4;             // 0,4,...,28
            float4 v = *reinterpret_cast<const float4*>(
                x + (size_t)(r0 + row) * D + k0 + kc);
            As[kc + 0][row] = v.x; As[kc + 1][row] = v.y;
            As[kc + 2][row] = v.z; As[kc + 3][row] = v.w;
            float4 w = *reinterpret_cast<const float4*>(
                x + (size_t)(c0 + row) * D + k0 + kc);
            Bs[kc + 0][row] = w.x; Bs[kc + 1][row] = w.y;
            Bs[kc + 2][row] = w.z; Bs[kc + 3][row] = w.w;
        }
        __syncthreads();
#pragma unroll
        for (int kk = 0; kk < BK; ++kk) {
            float4 a0 = *reinterpret_cast<const float4*>(&As[kk][ty * 8]);
            float4 a1 = *reinterpret_cast<const float4*>(&As[kk][ty * 8 + 4]);
            float4 b0 = *reinterpret_cast<const float4*>(&Bs[kk][tx * 8]);
            float4 b1 = *reinterpret_cast<const float4*>(&Bs[kk][tx * 8 + 4]);
            float a[8] = {a0.x, a0.y, a0.z, a0.w, a1.x, a1.y, a1.z, a1.w};
            float b[8] = {b0.x, b0.y, b0.z, b0.w, b1.x, b1.y, b1.z, b1.w};
#pragma unroll
            for (int i = 0; i < 8; ++i)
#pragma unroll
                for (int j = 0; j < 8; ++j)
                    acc[i][j] = fmaf(a[i], b[j], acc[i][j]);
        }
    }

    // epilogue: dist + masks + per-row min reduction
#pragma unroll
    for (int i = 0; i < 8; ++i) {
        int rm = ty * 8 + i;
        int rl = rlab[rm];
        float si = rsq[rm];
        float dp = rdp[rm];
        float thr_hi = dp + MARGIN;
        float mn = INFINITY, ms = INFINITY;
#pragma unroll
        for (int j = 0; j < 8; ++j) {
            int cn = tx * 8 + j;
            float sqd = fmaxf(si + csq[cn] - 2.0f * acc[i][j], 0.0f);
            float dist = sqd > 0.0f ? sqrtf(sqd) : 0.0f;
            if (rl != clab[cn]) {
                mn = fminf(mn, dist);
                if (dist > dp && dist < thr_hi) ms = fminf(ms, dist);
            }
        }
        // reduce across the 16 threads sharing this row (contiguous lanes)
        for (int m = 1; m <= 8; m <<= 1) {
            mn = fminf(mn, __shfl_xor(mn, m, 64));
            ms = fminf(ms, __shfl_xor(ms, m, 64));
        }
        if (tx == 0) {
            atomicMin(&minneg[r0 + rm], __float_as_int(mn));
            atomicMin(&minsemi[r0 + rm], __float_as_int(ms));
        }
    }
}

// ---------------------------------------------------------------------------
// Kernel 3: final scalar reduction.
// ---------------------------------------------------------------------------
__global__ __launch_bounds__(1024) void k_final(const float* __restrict__ dpos,
                                                const int* __restrict__ minneg,
                                                const int* __restrict__ minsemi,
                                                float* __restrict__ out) {
    __shared__ float ssum[1024];
    __shared__ float scnt[1024];
    int t = threadIdx.x;
    float s = 0.0f, c = 0.0f;
    for (int i = t; i < N; i += 1024) {
        float dp = dpos[i];
        float mn = __int_as_float(minneg[i]);
        float ms = __int_as_float(minsemi[i]);
        bool has_pos = dp >= 0.0f;
        bool has_neg = mn < INFINITY;
        if (has_pos && has_neg) {
            float dn = (ms < INFINITY) ? ms : mn;
            s += fmaxf(dp - dn + MARGIN, 0.0f);
            c += 1.0f;
        }
    }
    ssum[t] = s;
    scnt[t] = c;
    __syncthreads();
    for (int off = 512; off >= 1; off >>= 1) {
        if (t < off) {
            ssum[t] += ssum[t + off];
            scnt[t] += scnt[t + off];
        }
        __syncthreads();
    }
    if (t == 0) out[0] = ssum[0] / scnt[0];
}

// ---------------------------------------------------------------------------
extern "C" void kernel_launch(void* const* d_in, const int* in_sizes, int n_in,
                              void* d_out, int out_size, void* d_ws, size_t ws_size,
                              hipStream_t stream) {
    const float* x = (const float*)d_in[0];
    const int* labels = (const int*)d_in[1];
    float* out = (float*)d_out;

    // ws layout: sq[N] | dpos[N] | minneg[N] | minsemi[N]  (128 KB)
    float* sq = (float*)d_ws;
    float* dpos = sq + N;
    int* minneg = (int*)(dpos + N);
    int* minsemi = minneg + N;

    hipLaunchKernelGGL(k_dpos, dim3(N / 4), dim3(256), 0, stream,
                       x, labels, sq, dpos, minneg, minsemi);
    hipLaunchKernelGGL(k_main, dim3((N / BM) * (N / BN)), dim3(256), 0, stream,
                       x, labels, sq, dpos, minneg, minsemi);
    hipLaunchKernelGGL(k_final, dim3(1), dim3(1024), 0, stream,
                       dpos, minneg, minsemi, out);
}

// Round 2
// 302.944 us; speedup vs baseline: 1.6287x; 1.6287x over previous
//
#include <hip/hip_runtime.h>
#include <hip/hip_bf16.h>
#include <math.h>

#define N 8192
#define D 256
#define MARGIN 1.0f

#define BM 128
#define BN 128
#define BK 64   // bf16 elems per k-step (128 bytes per row)

typedef __attribute__((ext_vector_type(8))) short bhalf8;
typedef __attribute__((ext_vector_type(4))) float f32x4;

__device__ __forceinline__ unsigned short f2bf(float f) {
    return __builtin_bit_cast(unsigned short, __float2bfloat16(f));
}
__device__ __forceinline__ float bf2f(unsigned short u) {
    return __bfloat162float(__builtin_bit_cast(__hip_bfloat16, u));
}

// ---------------------------------------------------------------------------
// Kernel 0: split x (f32) into hi/lo bf16 planes. x = hi + lo + O(2^-18 x).
// ---------------------------------------------------------------------------
__global__ __launch_bounds__(256) void k_conv(const float* __restrict__ x,
                                              unsigned short* __restrict__ hi,
                                              unsigned short* __restrict__ lo) {
    int i = blockIdx.x * 256 + threadIdx.x;      // one float4 per thread
    float4 v = reinterpret_cast<const float4*>(x)[i];
    ushort4 h, l;
    h.x = f2bf(v.x); l.x = f2bf(v.x - bf2f(h.x));
    h.y = f2bf(v.y); l.y = f2bf(v.y - bf2f(h.y));
    h.z = f2bf(v.z); l.z = f2bf(v.z - bf2f(h.z));
    h.w = f2bf(v.w); l.w = f2bf(v.w - bf2f(h.w));
    reinterpret_cast<ushort4*>(hi)[i] = h;
    reinterpret_cast<ushort4*>(lo)[i] = l;
}

// ---------------------------------------------------------------------------
// Kernel 1: one wave per anchor (exact f32 path, ~0.2% of pair work).
//   sq[i] = ||x_i||^2 ; dpos[i] = max same-label dist (-1 if none);
//   init minneg/minsemi to +inf bits.
// ---------------------------------------------------------------------------
__global__ __launch_bounds__(256) void k_dpos(const float* __restrict__ x,
                                              const int* __restrict__ labels,
                                              float* __restrict__ sq,
                                              float* __restrict__ dpos,
                                              int* __restrict__ minneg,
                                              int* __restrict__ minsemi) {
    int wave = (blockIdx.x * blockDim.x + threadIdx.x) >> 6;
    int lane = threadIdx.x & 63;
    if (wave >= N) return;
    const int i = wave;

    float4 xi = reinterpret_cast<const float4*>(x + (size_t)i * D)[lane];
    float sqi = xi.x * xi.x + xi.y * xi.y + xi.z * xi.z + xi.w * xi.w;
    for (int m = 32; m >= 1; m >>= 1) sqi += __shfl_xor(sqi, m, 64);

    const int L = labels[i];
    float dp = -1.0f;

    for (int base = 0; base < N; base += 64) {
        int j = base + lane;
        int lj = labels[j];
        unsigned long long ball = __ballot(lj == L && j != i);
        while (ball) {
            int b = __ffsll(ball) - 1;
            ball &= ball - 1ull;
            int j2 = base + b;
            float4 xj = reinterpret_cast<const float4*>(x + (size_t)j2 * D)[lane];
            float dotp = xi.x * xj.x + xi.y * xj.y + xi.z * xj.z + xi.w * xj.w;
            for (int m = 32; m >= 1; m >>= 1) dotp += __shfl_xor(dotp, m, 64);
            float sqj = sq[0]; // placeholder avoided below; recompute instead
            (void)sqj;
            float sqjp = xj.x * xj.x + xj.y * xj.y + xj.z * xj.z + xj.w * xj.w;
            for (int m = 32; m >= 1; m >>= 1) sqjp += __shfl_xor(sqjp, m, 64);
            float sqd = fmaxf(sqi + sqjp - 2.0f * dotp, 0.0f);
            float dist = sqd > 0.0f ? sqrtf(sqd) : 0.0f;
            dp = fmaxf(dp, dist);
        }
    }

    if (lane == 0) {
        sq[i] = sqi;
        dpos[i] = dp;
        minneg[i] = 0x7F800000;
        minsemi[i] = 0x7F800000;
    }
}

// ---------------------------------------------------------------------------
// Kernel 2: bf16-split MFMA GEMM with fused semi-hard epilogue.
// 128x128 tile, BK=64, 4 waves (2x2), 16x16x32 bf16 MFMA, 4x4 frags/wave.
// K-loop: 12 steps = 3 phases {(hi,hi),(hi,lo),(lo,hi)} x 4 k-chunks of 64.
// LDS: linear dest for global_load_lds + XOR-swizzled global source;
// ds_read applies the same XOR (involution) -> conflict-free b128 reads.
// Epilogue in squared-distance space; atomicMin on float bits (>=0).
// ---------------------------------------------------------------------------
__global__ __launch_bounds__(256) void k_main(const unsigned short* __restrict__ hi,
                                              const unsigned short* __restrict__ lo,
                                              const int* __restrict__ labels,
                                              const float* __restrict__ sq,
                                              const float* __restrict__ dpos,
                                              int* __restrict__ minneg,
                                              int* __restrict__ minsemi) {
    __shared__ char As[BM * BK * 2];         // 16 KB
    __shared__ char Bs[BN * BK * 2];         // 16 KB
    __shared__ float rsq[BM], csq[BN], rdp2a[BM], rdp2b[BM];
    __shared__ int rlab[BM], clab[BN];

    const int nbx = N / BN;
    const int bx = blockIdx.x % nbx;
    const int by = blockIdx.x / nbx;
    const int r0 = by * BM, c0 = bx * BN;
    const int t = threadIdx.x;
    const int w = t >> 6, lane = t & 63;
    const int wr = w >> 1, wc = w & 1;      // 2x2 wave grid, 64x64 each

    if (t < BM) {
        rlab[t] = labels[r0 + t];
        rsq[t] = sq[r0 + t];
        float dp = dpos[r0 + t];
        rdp2a[t] = dp * dp;                  // dp = -1 sentinel -> (1, 0): semi never true
        float dh = dp + MARGIN;
        rdp2b[t] = dh * dh;
    } else {
        int u = t - BM;
        clab[u] = labels[c0 + u];
        csq[u] = sq[c0 + u];
    }

    f32x4 acc[4][4] = {};

    // swizzled source column (bytes) for this lane's 16B staging slot
    const int scb = ((lane & 7) ^ (lane >> 3)) << 4;

    for (int s = 0; s < 12; ++s) {
        const int phase = s >> 2;
        const int k0 = (s & 3) * BK;
        const unsigned short* Asrc = (phase < 2) ? hi : lo;
        const unsigned short* Bsrc = (phase == 1) ? lo : hi;

        __syncthreads();
#pragma unroll
        for (int q = 0; q < 4; ++q) {
            int chunk = q * 4 + w;                       // 16 chunks of 1KB
            int row = chunk * 8 + (lane >> 3);           // 0..127
            {
                const void* gp = Asrc + (size_t)(r0 + row) * D + k0 + (scb >> 1);
                void* lp = As + chunk * 1024 + lane * 16;
                __builtin_amdgcn_global_load_lds(
                    (__attribute__((address_space(1))) void*)(void*)gp,
                    (__attribute__((address_space(3))) void*)lp, 16, 0, 0);
            }
            {
                const void* gp = Bsrc + (size_t)(c0 + row) * D + k0 + (scb >> 1);
                void* lp = Bs + chunk * 1024 + lane * 16;
                __builtin_amdgcn_global_load_lds(
                    (__attribute__((address_space(1))) void*)(void*)gp,
                    (__attribute__((address_space(3))) void*)lp, 16, 0, 0);
            }
        }
        __syncthreads();

#pragma unroll
        for (int kk = 0; kk < 2; ++kk) {
            bhalf8 a[4], b[4];
            const int cb = kk * 64 + ((lane >> 4) << 4);  // byte col of 16B k-slice
#pragma unroll
            for (int m = 0; m < 4; ++m) {
                int ra = wr * 64 + m * 16 + (lane & 15);
                a[m] = *reinterpret_cast<const bhalf8*>(
                    As + (ra << 7) + (cb ^ ((ra & 7) << 4)));
                int rb = wc * 64 + m * 16 + (lane & 15);
                b[m] = *reinterpret_cast<const bhalf8*>(
                    Bs + (rb << 7) + (cb ^ ((rb & 7) << 4)));
            }
#pragma unroll
            for (int m = 0; m < 4; ++m)
#pragma unroll
                for (int n = 0; n < 4; ++n)
                    acc[m][n] = __builtin_amdgcn_mfma_f32_16x16x32_bf16(
                        a[m], b[n], acc[m][n], 0, 0, 0);
        }
    }

    // ---- epilogue: squared-distance space, per-row min over 64 cols ----
    const int g = lane >> 4, c = lane & 15;
    const float INF = __builtin_inff();
#pragma unroll
    for (int m = 0; m < 4; ++m) {
#pragma unroll
        for (int reg = 0; reg < 4; ++reg) {
            const int row = wr * 64 + m * 16 + g * 4 + reg;   // local row
            const float si = rsq[row];
            const int rl = rlab[row];
            const float dp2 = rdp2a[row], dphi2 = rdp2b[row];
            float mn = INF, ms = INF;
#pragma unroll
            for (int nn = 0; nn < 4; ++nn) {
                const int col = wc * 64 + nn * 16 + c;
                float sqd = fmaxf(si + csq[col] - 2.0f * acc[m][nn][reg], 0.0f);
                bool neq = (rl != clab[col]);
                mn = fminf(mn, neq ? sqd : INF);
                bool semi = neq && (sqd > dp2) && (sqd < dphi2);
                ms = fminf(ms, semi ? sqd : INF);
            }
#pragma unroll
            for (int msk = 1; msk <= 8; msk <<= 1) {
                mn = fminf(mn, __shfl_xor(mn, msk, 64));
                ms = fminf(ms, __shfl_xor(ms, msk, 64));
            }
            if (c == 0) {
                atomicMin(&minneg[r0 + row], __float_as_int(mn));
                atomicMin(&minsemi[r0 + row], __float_as_int(ms));
            }
        }
    }
}

// ---------------------------------------------------------------------------
// Kernel 3: final scalar reduction (minima are SQUARED distances here).
// ---------------------------------------------------------------------------
__global__ __launch_bounds__(1024) void k_final(const float* __restrict__ dpos,
                                                const int* __restrict__ minneg,
                                                const int* __restrict__ minsemi,
                                                float* __restrict__ out) {
    __shared__ float ssum[1024];
    __shared__ float scnt[1024];
    int t = threadIdx.x;
    float s = 0.0f, cn = 0.0f;
    for (int i = t; i < N; i += 1024) {
        float dp = dpos[i];
        float mnq = __int_as_float(minneg[i]);
        float msq = __int_as_float(minsemi[i]);
        bool has_pos = dp >= 0.0f;
        bool has_neg = mnq < __builtin_inff();
        if (has_pos && has_neg) {
            float dnq = (msq < __builtin_inff()) ? msq : mnq;
            float dn = sqrtf(dnq);
            s += fmaxf(dp - dn + MARGIN, 0.0f);
            cn += 1.0f;
        }
    }
    ssum[t] = s;
    scnt[t] = cn;
    __syncthreads();
    for (int off = 512; off >= 1; off >>= 1) {
        if (t < off) {
            ssum[t] += ssum[t + off];
            scnt[t] += scnt[t + off];
        }
        __syncthreads();
    }
    if (t == 0) out[0] = ssum[0] / scnt[0];
}

// ---------------------------------------------------------------------------
extern "C" void kernel_launch(void* const* d_in, const int* in_sizes, int n_in,
                              void* d_out, int out_size, void* d_ws, size_t ws_size,
                              hipStream_t stream) {
    const float* x = (const float*)d_in[0];
    const int* labels = (const int*)d_in[1];
    float* out = (float*)d_out;

    // ws: sq[N] | dpos[N] | minneg[N] | minsemi[N] | hi[N*D] bf16 | lo[N*D] bf16
    float* sq = (float*)d_ws;
    float* dpos = sq + N;
    int* minneg = (int*)(dpos + N);
    int* minsemi = minneg + N;
    unsigned short* hi = (unsigned short*)(minsemi + N);
    unsigned short* lo = hi + (size_t)N * D;

    hipLaunchKernelGGL(k_conv, dim3(N * D / 4 / 256), dim3(256), 0, stream, x, hi, lo);
    hipLaunchKernelGGL(k_dpos, dim3(N / 4), dim3(256), 0, stream,
                       x, labels, sq, dpos, minneg, minsemi);
    hipLaunchKernelGGL(k_main, dim3((N / BM) * (N / BN)), dim3(256), 0, stream,
                       hi, lo, labels, sq, dpos, minneg, minsemi);
    hipLaunchKernelGGL(k_final, dim3(1), dim3(1024), 0, stream,
                       dpos, minneg, minsemi, out);
}

// Round 3
// 177.519 us; speedup vs baseline: 2.7794x; 1.7066x over previous
//
#include <hip/hip_runtime.h>
#include <hip/hip_bf16.h>
#include <math.h>

#define N 8192
#define D 256
#define MARGIN 1.0f

#define BM 128
#define BN 128
#define BK 64   // bf16 elems per k-chunk (128 bytes per row)
#define NB (N / BM)   // 64 tiles per dim

typedef __attribute__((ext_vector_type(8))) short bhalf8;
typedef __attribute__((ext_vector_type(4))) float f32x4;

__device__ __forceinline__ unsigned short f2bf(float f) {
    return __builtin_bit_cast(unsigned short, __float2bfloat16(f));
}
__device__ __forceinline__ float bf2f(unsigned short u) {
    return __bfloat162float(__builtin_bit_cast(__hip_bfloat16, u));
}

// ---------------------------------------------------------------------------
// Kernel 0: split x (f32) into hi/lo bf16 planes. x = hi + lo + O(2^-18 x).
// ---------------------------------------------------------------------------
__global__ __launch_bounds__(256) void k_conv(const float* __restrict__ x,
                                              unsigned short* __restrict__ hi,
                                              unsigned short* __restrict__ lo) {
    int i = blockIdx.x * 256 + threadIdx.x;
    float4 v = reinterpret_cast<const float4*>(x)[i];
    ushort4 h, l;
    h.x = f2bf(v.x); l.x = f2bf(v.x - bf2f(h.x));
    h.y = f2bf(v.y); l.y = f2bf(v.y - bf2f(h.y));
    h.z = f2bf(v.z); l.z = f2bf(v.z - bf2f(h.z));
    h.w = f2bf(v.w); l.w = f2bf(v.w - bf2f(h.w));
    reinterpret_cast<ushort4*>(hi)[i] = h;
    reinterpret_cast<ushort4*>(lo)[i] = l;
}

// ---------------------------------------------------------------------------
// Kernel 1: one wave per anchor (exact f32 path, ~0.2% of pair work).
// ---------------------------------------------------------------------------
__global__ __launch_bounds__(256) void k_dpos(const float* __restrict__ x,
                                              const int* __restrict__ labels,
                                              float* __restrict__ sq,
                                              float* __restrict__ dpos,
                                              int* __restrict__ minneg,
                                              int* __restrict__ minsemi) {
    int wave = (blockIdx.x * blockDim.x + threadIdx.x) >> 6;
    int lane = threadIdx.x & 63;
    if (wave >= N) return;
    const int i = wave;

    float4 xi = reinterpret_cast<const float4*>(x + (size_t)i * D)[lane];
    float sqi = xi.x * xi.x + xi.y * xi.y + xi.z * xi.z + xi.w * xi.w;
    for (int m = 32; m >= 1; m >>= 1) sqi += __shfl_xor(sqi, m, 64);

    const int L = labels[i];
    float dp = -1.0f;

    for (int base = 0; base < N; base += 64) {
        int j = base + lane;
        int lj = labels[j];
        unsigned long long ball = __ballot(lj == L && j != i);
        while (ball) {
            int b = __ffsll(ball) - 1;
            ball &= ball - 1ull;
            int j2 = base + b;
            float4 xj = reinterpret_cast<const float4*>(x + (size_t)j2 * D)[lane];
            float dotp = xi.x * xj.x + xi.y * xj.y + xi.z * xj.z + xi.w * xj.w;
            float sqjp = xj.x * xj.x + xj.y * xj.y + xj.z * xj.z + xj.w * xj.w;
            for (int m = 32; m >= 1; m >>= 1) {
                dotp += __shfl_xor(dotp, m, 64);
                sqjp += __shfl_xor(sqjp, m, 64);
            }
            float sqd = fmaxf(sqi + sqjp - 2.0f * dotp, 0.0f);
            float dist = sqd > 0.0f ? sqrtf(sqd) : 0.0f;
            dp = fmaxf(dp, dist);
        }
    }

    if (lane == 0) {
        sq[i] = sqi;
        dpos[i] = dp;
        minneg[i] = 0x7F800000;
        minsemi[i] = 0x7F800000;
    }
}

// ---------------------------------------------------------------------------
// Kernel 2: symmetric bf16-split MFMA GEMM + fused semi-hard epilogue.
// Only upper-triangular tiles (by <= bx); each tile updates BOTH row-anchors
// and col-anchors. Per k-chunk (BK=64): stage Ah/Al/Bh/Bl once, run 3 MFMA
// phases (hh, h*lo, lo*h) with register reuse -> 96 MFMAs per barrier pair.
// LDS: linear dest + XOR-pre-swizzled global source; reads apply same XOR.
// Epilogue in squared-distance space; int-bits atomicMin (values >= 0).
// ---------------------------------------------------------------------------
__global__ __launch_bounds__(256) void k_main(const unsigned short* __restrict__ hi,
                                              const unsigned short* __restrict__ lo,
                                              const int* __restrict__ labels,
                                              const float* __restrict__ sq,
                                              const float* __restrict__ dpos,
                                              int* __restrict__ minneg,
                                              int* __restrict__ minsemi) {
    __shared__ char Ah[BM * BK * 2];   // 16 KB each
    __shared__ char Al[BM * BK * 2];
    __shared__ char Bh[BN * BK * 2];
    __shared__ char Bl[BN * BK * 2];
    __shared__ float rsq[BM], csq[BN];
    __shared__ float rdp2a[BM], rdp2b[BM], cdp2a[BN], cdp2b[BN];
    __shared__ int rlab[BM], clab[BN];

    // triangular decode: t -> (by, bx), by <= bx
    const int t = threadIdx.x;
    int tb = blockIdx.x;
    int by = (int)((2 * NB + 1 - sqrtf((float)((2 * NB + 1) * (2 * NB + 1)) -
                                       8.0f * (float)tb)) * 0.5f);
    if (by < 0) by = 0;
    if (by > NB - 1) by = NB - 1;
    while (by > 0 && (by * NB - by * (by - 1) / 2) > tb) --by;
    while (((by + 1) * NB - (by + 1) * by / 2) <= tb) ++by;
    const int bx = by + (tb - (by * NB - by * (by - 1) / 2));
    const int r0 = by * BM, c0 = bx * BN;

    const int w = t >> 6, lane = t & 63;
    const int wr = w >> 1, wc = w & 1;

    if (t < BM) {
        rlab[t] = labels[r0 + t];
        rsq[t] = sq[r0 + t];
        float dp = dpos[r0 + t];
        rdp2a[t] = dp * dp;
        float dh = dp + MARGIN;
        rdp2b[t] = dh * dh;
    } else {
        int u = t - BM;
        clab[u] = labels[c0 + u];
        csq[u] = sq[c0 + u];
        float dp = dpos[c0 + u];
        cdp2a[u] = dp * dp;
        float dh = dp + MARGIN;
        cdp2b[u] = dh * dh;
    }

    f32x4 acc[4][4] = {};

    const int scb = ((lane & 7) ^ (lane >> 3)) << 4;   // swizzled src col (bytes)

#pragma unroll 1
    for (int s = 0; s < 4; ++s) {
        const int k0 = s * BK;
        __syncthreads();
#pragma unroll
        for (int q = 0; q < 4; ++q) {
            int chunk = q * 4 + w;                 // 16 chunks of 1 KB per buffer
            int row = chunk * 8 + (lane >> 3);
            size_t roff = (size_t)(r0 + row) * D + k0 + (scb >> 1);
            size_t coff = (size_t)(c0 + row) * D + k0 + (scb >> 1);
            int loff = chunk * 1024 + lane * 16;
            __builtin_amdgcn_global_load_lds(
                (__attribute__((address_space(1))) void*)(void*)(hi + roff),
                (__attribute__((address_space(3))) void*)(Ah + loff), 16, 0, 0);
            __builtin_amdgcn_global_load_lds(
                (__attribute__((address_space(1))) void*)(void*)(lo + roff),
                (__attribute__((address_space(3))) void*)(Al + loff), 16, 0, 0);
            __builtin_amdgcn_global_load_lds(
                (__attribute__((address_space(1))) void*)(void*)(hi + coff),
                (__attribute__((address_space(3))) void*)(Bh + loff), 16, 0, 0);
            __builtin_amdgcn_global_load_lds(
                (__attribute__((address_space(1))) void*)(void*)(lo + coff),
                (__attribute__((address_space(3))) void*)(Bl + loff), 16, 0, 0);
        }
        __syncthreads();

#pragma unroll
        for (int kk = 0; kk < 2; ++kk) {
            const int cb = kk * 64 + ((lane >> 4) << 4);
            bhalf8 aH[4], bH[4], aL[4], bL[4];
#pragma unroll
            for (int m = 0; m < 4; ++m) {
                int ra = wr * 64 + m * 16 + (lane & 15);
                int rb = wc * 64 + m * 16 + (lane & 15);
                aH[m] = *reinterpret_cast<const bhalf8*>(Ah + (ra << 7) + (cb ^ ((ra & 7) << 4)));
                bH[m] = *reinterpret_cast<const bhalf8*>(Bh + (rb << 7) + (cb ^ ((rb & 7) << 4)));
            }
#pragma unroll
            for (int m = 0; m < 4; ++m)
#pragma unroll
                for (int n = 0; n < 4; ++n)
                    acc[m][n] = __builtin_amdgcn_mfma_f32_16x16x32_bf16(aH[m], bH[n], acc[m][n], 0, 0, 0);
#pragma unroll
            for (int m = 0; m < 4; ++m) {
                int rb = wc * 64 + m * 16 + (lane & 15);
                bL[m] = *reinterpret_cast<const bhalf8*>(Bl + (rb << 7) + (cb ^ ((rb & 7) << 4)));
            }
#pragma unroll
            for (int m = 0; m < 4; ++m)
#pragma unroll
                for (int n = 0; n < 4; ++n)
                    acc[m][n] = __builtin_amdgcn_mfma_f32_16x16x32_bf16(aH[m], bL[n], acc[m][n], 0, 0, 0);
#pragma unroll
            for (int m = 0; m < 4; ++m) {
                int ra = wr * 64 + m * 16 + (lane & 15);
                aL[m] = *reinterpret_cast<const bhalf8*>(Al + (ra << 7) + (cb ^ ((ra & 7) << 4)));
            }
#pragma unroll
            for (int m = 0; m < 4; ++m)
#pragma unroll
                for (int n = 0; n < 4; ++n)
                    acc[m][n] = __builtin_amdgcn_mfma_f32_16x16x32_bf16(aL[m], bH[n], acc[m][n], 0, 0, 0);
        }
    }

    // ---- epilogue: squared-distance space ----
    const int g = lane >> 4, c = lane & 15;
    const float INF = __builtin_inff();

    // row pass: per row, min over this wave's 64 cols
#pragma unroll
    for (int m = 0; m < 4; ++m) {
#pragma unroll
        for (int reg = 0; reg < 4; ++reg) {
            const int row = wr * 64 + m * 16 + g * 4 + reg;
            const float si = rsq[row];
            const int rl = rlab[row];
            const float dp2 = rdp2a[row], dphi2 = rdp2b[row];
            float mn = INF, ms = INF;
#pragma unroll
            for (int nn = 0; nn < 4; ++nn) {
                const int col = wc * 64 + nn * 16 + c;
                float sqd = fmaxf(si + csq[col] - 2.0f * acc[m][nn][reg], 0.0f);
                bool neq = (rl != clab[col]);
                mn = fminf(mn, neq ? sqd : INF);
                bool semi = neq && (sqd > dp2) && (sqd < dphi2);
                ms = fminf(ms, semi ? sqd : INF);
            }
#pragma unroll
            for (int msk = 1; msk <= 8; msk <<= 1) {
                mn = fminf(mn, __shfl_xor(mn, msk, 64));
                ms = fminf(ms, __shfl_xor(ms, msk, 64));
            }
            if (c == 0) {
                atomicMin(&minneg[r0 + row], __float_as_int(mn));
                atomicMin(&minsemi[r0 + row], __float_as_int(ms));
            }
        }
    }

    // col pass: per col, min over this wave's 64 rows (anchor = col element)
#pragma unroll
    for (int n = 0; n < 4; ++n) {
        const int col = wc * 64 + n * 16 + c;
        const float sj = csq[col];
        const int cl = clab[col];
        const float dp2 = cdp2a[col], dphi2 = cdp2b[col];
        float mn = INF, ms = INF;
#pragma unroll
        for (int m = 0; m < 4; ++m) {
#pragma unroll
            for (int reg = 0; reg < 4; ++reg) {
                const int row = wr * 64 + m * 16 + g * 4 + reg;
                float sqd = fmaxf(rsq[row] + sj - 2.0f * acc[m][n][reg], 0.0f);
                bool neq = (cl != rlab[row]);
                mn = fminf(mn, neq ? sqd : INF);
                bool semi = neq && (sqd > dp2) && (sqd < dphi2);
                ms = fminf(ms, semi ? sqd : INF);
            }
        }
        mn = fminf(mn, __shfl_xor(mn, 16, 64));
        mn = fminf(mn, __shfl_xor(mn, 32, 64));
        ms = fminf(ms, __shfl_xor(ms, 16, 64));
        ms = fminf(ms, __shfl_xor(ms, 32, 64));
        if (g == 0) {
            atomicMin(&minneg[c0 + col], __float_as_int(mn));
            atomicMin(&minsemi[c0 + col], __float_as_int(ms));
        }
    }
}

// ---------------------------------------------------------------------------
// Kernel 3: final scalar reduction (minima are SQUARED distances).
// ---------------------------------------------------------------------------
__global__ __launch_bounds__(1024) void k_final(const float* __restrict__ dpos,
                                                const int* __restrict__ minneg,
                                                const int* __restrict__ minsemi,
                                                float* __restrict__ out) {
    __shared__ float ssum[1024];
    __shared__ float scnt[1024];
    int t = threadIdx.x;
    float s = 0.0f, cn = 0.0f;
    for (int i = t; i < N; i += 1024) {
        float dp = dpos[i];
        float mnq = __int_as_float(minneg[i]);
        float msq = __int_as_float(minsemi[i]);
        bool has_pos = dp >= 0.0f;
        bool has_neg = mnq < __builtin_inff();
        if (has_pos && has_neg) {
            float dnq = (msq < __builtin_inff()) ? msq : mnq;
            float dn = sqrtf(dnq);
            s += fmaxf(dp - dn + MARGIN, 0.0f);
            cn += 1.0f;
        }
    }
    ssum[t] = s;
    scnt[t] = cn;
    __syncthreads();
    for (int off = 512; off >= 1; off >>= 1) {
        if (t < off) {
            ssum[t] += ssum[t + off];
            scnt[t] += scnt[t + off];
        }
        __syncthreads();
    }
    if (t == 0) out[0] = ssum[0] / scnt[0];
}

// ---------------------------------------------------------------------------
extern "C" void kernel_launch(void* const* d_in, const int* in_sizes, int n_in,
                              void* d_out, int out_size, void* d_ws, size_t ws_size,
                              hipStream_t stream) {
    const float* x = (const float*)d_in[0];
    const int* labels = (const int*)d_in[1];
    float* out = (float*)d_out;

    float* sq = (float*)d_ws;
    float* dpos = sq + N;
    int* minneg = (int*)(dpos + N);
    int* minsemi = minneg + N;
    unsigned short* hi = (unsigned short*)(minsemi + N);
    unsigned short* lo = hi + (size_t)N * D;

    hipLaunchKernelGGL(k_conv, dim3(N * D / 4 / 256), dim3(256), 0, stream, x, hi, lo);
    hipLaunchKernelGGL(k_dpos, dim3(N / 4), dim3(256), 0, stream,
                       x, labels, sq, dpos, minneg, minsemi);
    hipLaunchKernelGGL(k_main, dim3(NB * (NB + 1) / 2), dim3(256), 0, stream,
                       hi, lo, labels, sq, dpos, minneg, minsemi);
    hipLaunchKernelGGL(k_final, dim3(1), dim3(1024), 0, stream,
                       dpos, minneg, minsemi, out);
}